// Round 1
// baseline (662.786 us; speedup 1.0000x reference)
//
#include <hip/hip_runtime.h>
#include <math.h>

// Program interpreter: B=1M rows, 19 steps of MLP(2->64->64->3) + argmax walk.
// fp32 emulated on f16 MFMA, 2-limb splits (lo limb scaled 2^12, RTZ pack).
//
// R9: serial-chain diet (kernel is latency-bound at 2 waves/SIMD; issue work
// is ~10x below wall time). Three chain cuts, all f32-reassociation-safe:
//  (1) cross-replica reduce via v_permlane16/32_swap (VALU pipe) instead of
//      ds_swizzle + ds_bpermute -- removes all DS ops + lgkm waits from loop.
//  (2) accB limb-product chain 4-deep -> two 2-deep MFMA chains + pk_add tree.
//  (3) combine+diff-dot fused per t-tile, split even/odd dot accumulators:
//      dots issue as each tile's accs land; h2 staging array eliminated
//      (last step re-derives h2 from the still-live acc frags).

#define NSTEPS 19

typedef _Float16 half8   __attribute__((ext_vector_type(8)));
typedef _Float16 half2v  __attribute__((ext_vector_type(2)));
typedef float    float2v __attribute__((ext_vector_type(2)));
typedef float    float4v __attribute__((ext_vector_type(4)));
typedef unsigned int uint2v __attribute__((ext_vector_type(2)));

__device__ __forceinline__ half2v pkrtz(float a, float b) {
    return __builtin_bit_cast(half2v, __builtin_amdgcn_cvt_pkrtz(a, b));
}
__device__ __forceinline__ float2v lo2(float4v v) {
    return __builtin_shufflevector(v, v, 0, 1);
}
__device__ __forceinline__ float2v hi2(float4v v) {
    return __builtin_shufflevector(v, v, 2, 3);
}

// Sum over the 4 k-replica groups: +(lane^16) then +(lane^32).
// gfx950 permlane*_swap: one instruction yields both exchanged registers, so
// out[0]+out[1] == g + swap(g) bitwise (fp add commutes). Pure VALU latency
// (~4 cyc/inst) vs ds_swizzle/ds_bpermute (~60 cyc + lgkm wait each).
__device__ __forceinline__ float xsum48(float g) {
#if __has_builtin(__builtin_amdgcn_permlane16_swap) && \
    __has_builtin(__builtin_amdgcn_permlane32_swap)
    unsigned u = __builtin_bit_cast(unsigned, g);
    uint2v a = __builtin_amdgcn_permlane16_swap(u, u, false, false);
    g = __builtin_bit_cast(float, (unsigned)a[0]) +
        __builtin_bit_cast(float, (unsigned)a[1]);
    unsigned v = __builtin_bit_cast(unsigned, g);
    uint2v b = __builtin_amdgcn_permlane32_swap(v, v, false, false);
    return __builtin_bit_cast(float, (unsigned)b[0]) +
           __builtin_bit_cast(float, (unsigned)b[1]);
#else
    // fallback: DS-pipe butterfly (R8 path)
    int r = __builtin_amdgcn_ds_swizzle(__builtin_bit_cast(int, g), 0x401F);
    g += __builtin_bit_cast(float, r);
    g += __shfl_xor(g, 32, 64);
    return g;
#endif
}

__global__ __launch_bounds__(256, 2)
void program_kernel(const float* __restrict__ x,
                    const float* __restrict__ W1,
                    const float* __restrict__ b1,
                    const float* __restrict__ W2,
                    const float* __restrict__ b2,
                    const float* __restrict__ W3,
                    const float* __restrict__ b3,
                    float* __restrict__ out,
                    int B) {
    const int tid    = threadIdx.x;
    const int lane   = tid & 63;
    const int wave   = tid >> 6;
    const int lanelo = lane & 15;   // m: my batch row within the tile
    const int q8     = lane >> 4;   // k-slice / replica group 0..3
    const int myRow  = blockIdx.x * 64 + wave * 16 + lanelo;
    const int rowLd  = myRow < B ? myRow : (B - 1);

    // ---- w1 tables as pairs (VGPR): pair i of kf-half: k = kf*32+q8*8+2i ----
    float2v w1a[8], w1b[8], b1v[8];
    #pragma unroll
    for (int kf = 0; kf < 2; ++kf) {
        const int k0 = kf * 32 + q8 * 8;
        const float2v* a = (const float2v*)(W1 + k0);
        const float2v* bb = (const float2v*)(W1 + 64 + k0);
        const float2v* bv = (const float2v*)(b1 + k0);
        #pragma unroll
        for (int i = 0; i < 4; ++i) {
            w1a[kf * 4 + i] = a[i];
            w1b[kf * 4 + i] = bb[i];
            b1v[kf * 4 + i] = bv[i];
        }
    }

    // ---- W2^T limb A-frags (MFMA-only; AGPR-eligible) ----
    half8 Wh[2][4], Wl[2][4];
    #pragma unroll
    for (int kf = 0; kf < 2; ++kf) {
        #pragma unroll
        for (int t = 0; t < 4; ++t) {
            half8 bh, bl;
            #pragma unroll
            for (int j = 0; j < 8; ++j) {
                const float w =
                    W2[(kf * 32 + q8 * 8 + j) * 64 + t * 16 + lanelo];
                const _Float16 wh = (_Float16)w;                       // RNE
                const _Float16 wl = (_Float16)((w - (float)wh) * 4096.0f);
                bh[j] = wh;
                bl[j] = wl;
            }
            Wh[kf][t] = bh;
            Wl[kf][t] = bl;
        }
    }

    // ---- b2 C-init frags (MFMA-C only) ----
    float4v b2f[4];
    #pragma unroll
    for (int t = 0; t < 4; ++t) {
        const int n = t * 16 + q8 * 4;
        b2f[t] = (float4v){b2[n], b2[n + 1], b2[n + 2], b2[n + 3]};
    }

    // ---- W3 difference tables (VGPR): my n-set n = 16t+4*q8+r, pairs ----
    float2v d10[8], d20[8];
    #pragma unroll
    for (int p = 0; p < 8; ++p) {
        const int n0 = (p >> 1) * 16 + q8 * 4 + (p & 1) * 2;
        const float w00 = W3[n0 * 3 + 0],       w01 = W3[n0 * 3 + 1];
        const float w02 = W3[n0 * 3 + 2];
        const float w10 = W3[(n0 + 1) * 3 + 0], w11 = W3[(n0 + 1) * 3 + 1];
        const float w12 = W3[(n0 + 1) * 3 + 2];
        d10[p] = (float2v){w01 - w00, w11 - w10};
        d20[p] = (float2v){w02 - w00, w12 - w10};
    }
    const float b3v0 = b3[0];
    const float db10 = b3[1] - b3[0];
    const float db20 = b3[2] - b3[0];

    // ---- initial row state (4x replicated across q8 groups) ----
    float pos, fwd, c5;
    {
        const float* xr = x + (size_t)rowLd * 6;
        pos = xr[0];
        fwd = xr[1];
        c5  = xr[5];
    }

    const float4v zf = {0.f, 0.f, 0.f, 0.f};
    const float2v z2 = {0.f, 0.f};
    const float2v kinv = {1.0f / 4096.0f, 1.0f / 4096.0f};
    float l0 = 0.f, l1 = 0.f, l2 = 0.f;

    #pragma unroll 1
    for (int step = 0; step < NSTEPS; ++step) {
        // ---- layer 1 (packed) + 2-limb split -> B-frag limbs ----
        const float2v posp = {pos, pos}, fwdp = {fwd, fwd};
        half8 Hh[2], Hl[2];
        #pragma unroll
        for (int kf = 0; kf < 2; ++kf) {
            union { half8 v; half2v h2[4]; } uh, ul;
            #pragma unroll
            for (int p = 0; p < 4; ++p) {
                const int e = kf * 4 + p;
                float2v z = __builtin_elementwise_fma(fwdp, w1b[e], b1v[e]);
                z = __builtin_elementwise_fma(posp, w1a[e], z);
                const float2v hp = __builtin_elementwise_max(z, z2);
                uh.h2[p] = pkrtz(hp[0], hp[1]);
                // residuals (hi-half f16 extract folds into v_fma_mix)
                const float r0 = fmaf((float)uh.h2[p][0], -1.0f, hp[0]);
                const float r1 = fmaf((float)uh.h2[p][1], -1.0f, hp[1]);
                const float2v rp = (float2v){r0, r1} * 4096.0f;  // pk_mul
                ul.h2[p] = pkrtz(rp[0], rp[1]);
            }
            Hh[kf] = uh.v;
            Hl[kf] = ul.v;
        }

        // ---- layer 2 via MFMA: balanced 2-deep chains (tree) ----
        // accB = (Wl0*Hh0 + Wh0*Hl0) + (Wl1*Hh1 + Wh1*Hl1)   [2-deep + add]
        // accA = b2 + Wh0*Hh0 + Wh1*Hh1                        [2-deep]
        float4v accA[4], accB1[4], accB2[4];
        #pragma unroll
        for (int t = 0; t < 4; ++t) {
            accB1[t] = __builtin_amdgcn_mfma_f32_16x16x32_f16(
                Wl[0][t], Hh[0], zf, 0, 0, 0);
            accB1[t] = __builtin_amdgcn_mfma_f32_16x16x32_f16(
                Wh[0][t], Hl[0], accB1[t], 0, 0, 0);
            accB2[t] = __builtin_amdgcn_mfma_f32_16x16x32_f16(
                Wl[1][t], Hh[1], zf, 0, 0, 0);
            accB2[t] = __builtin_amdgcn_mfma_f32_16x16x32_f16(
                Wh[1][t], Hl[1], accB2[t], 0, 0, 0);
            accA[t] = __builtin_amdgcn_mfma_f32_16x16x32_f16(
                Wh[0][t], Hh[0], b2f[t], 0, 0, 0);
            accA[t] = __builtin_amdgcn_mfma_f32_16x16x32_f16(
                Wh[1][t], Hh[1], accA[t], 0, 0, 0);
        }

        // ---- fused combine + diff-dots per t-tile, split accumulators ----
        float2v s1x = z2, s1y = z2, s2x = z2, s2y = z2;
        #pragma unroll
        for (int t = 0; t < 4; ++t) {
            const float4v aB = accB1[t] + accB2[t];            // pk_add tree
            const float2v h0 = __builtin_elementwise_max(
                __builtin_elementwise_fma(lo2(aB), kinv, lo2(accA[t])), z2);
            const float2v h1 = __builtin_elementwise_max(
                __builtin_elementwise_fma(hi2(aB), kinv, hi2(accA[t])), z2);
            s1x = __builtin_elementwise_fma(h0, d10[2 * t], s1x);
            s1y = __builtin_elementwise_fma(h1, d10[2 * t + 1], s1y);
            s2x = __builtin_elementwise_fma(h0, d20[2 * t], s2x);
            s2y = __builtin_elementwise_fma(h1, d20[2 * t + 1], s2y);
        }
        const float2v s1 = s1x + s1y;
        const float2v s2 = s2x + s2y;
        float g10 = s1[0] + s1[1];
        float g20 = s2[0] + s2[1];
        g10 = xsum48(g10) + db10;   // = l1 - l0
        g20 = xsum48(g20) + db20;   // = l2 - l0

        // ---- last step: reconstruct full logits for the output probs ----
        // (re-derive h2 from the still-live acc frags; one-time cost)
        if (step == NSTEPS - 1) {
            float2v s0x = z2, s0y = z2;
            #pragma unroll
            for (int t = 0; t < 4; ++t) {
                const float4v aB = accB1[t] + accB2[t];
                const float2v h0 = __builtin_elementwise_max(
                    __builtin_elementwise_fma(lo2(aB), kinv, lo2(accA[t])), z2);
                const float2v h1 = __builtin_elementwise_max(
                    __builtin_elementwise_fma(hi2(aB), kinv, hi2(accA[t])), z2);
                const int n0 = t * 16 + q8 * 4;
                const float2v w3a = {W3[n0 * 3],       W3[(n0 + 1) * 3]};
                const float2v w3b = {W3[(n0 + 2) * 3], W3[(n0 + 3) * 3]};
                s0x = __builtin_elementwise_fma(h0, w3a, s0x);
                s0y = __builtin_elementwise_fma(h1, w3b, s0y);
            }
            const float2v s0 = s0x + s0y;
            float t0 = s0[0] + s0[1];
            t0 = xsum48(t0);
            l0 = t0 + b3v0;
            l1 = l0 + g10;
            l2 = l0 + g20;
        }

        // ---- decision: l2 > max(l0,l1) <=> g20 > max(0,g10);
        //      l1 > l0 <=> g10 > 0 (first-max-wins preserved) ----
        const float delta =
            (g20 > fmaxf(0.f, g10)) ? 1.0f : ((g10 > 0.f) ? 0.0f : -1.0f);
        pos += delta;
        fwd += 1.0f;
    }

    // ---- epilogue: all lanes have their row's logits; q8==0 stores ----
    if (q8 == 0 && myRow < B) {
        const float p0 = 1.f / (1.f + __expf(-l0));
        const float p1 = 1.f / (1.f + __expf(-l1));
        const float p2 = 1.f / (1.f + __expf(-l2));
        float2* o = (float2*)(out + (size_t)myRow * 6);
        o[0] = make_float2(pos, fwd);
        o[1] = make_float2(p0, p1);
        o[2] = make_float2(p2, c5 + (float)NSTEPS);
    }
}

extern "C" void kernel_launch(void* const* d_in, const int* in_sizes, int n_in,
                              void* d_out, int out_size, void* d_ws, size_t ws_size,
                              hipStream_t stream) {
    const float* x  = (const float*)d_in[0];
    const float* W1 = (const float*)d_in[1];
    const float* b1 = (const float*)d_in[2];
    const float* W2 = (const float*)d_in[3];
    const float* b2 = (const float*)d_in[4];
    const float* W3 = (const float*)d_in[5];
    const float* b3 = (const float*)d_in[6];
    float* out = (float*)d_out;

    const int B = in_sizes[0] / 6;              // 1048576
    const int nBlocks = (B + 63) / 64;          // 64 rows/block (4 waves x 16)

    program_kernel<<<nBlocks, 256, 0, stream>>>(
        x, W1, b1, W2, b2, W3, b3, out, B);
}